// Round 11
// baseline (5015.706 us; speedup 1.0000x reference)
//
#include <hip/hip_runtime.h>
#include <hip/hip_fp16.h>

// CYK net: L=64, B=32, DIN=D=FFS=512
//   P[cell] = table[cell] @ WcL.T (row-tri layout); Qt[cell] = table[cell] @ WcR.T (col-tri layout)
//   node(j,s) = bc + max_k ( P[j,j+k] + Qt[j+k+1,j+s] )   -- BOTH streams contiguous in k
//   [vals|P|Qt] = node @ BigB + biasBig   (bf16x3 MFMA)
// R10 -> R11: (1) Qt col-triangle layout (contiguous Q stream); (2) last-block
// reduction replaces k_node_red (gbar-style release/acquire protocol, per-cell);
// (3) KC>1 levels fuse GEMM into the last block (12 tiles/wave). 168 -> ~105 dispatches.

#define Lx 64
#define Bb 32
#define CELLSZ (Bb*512)         // 16384 elems per cell tile

typedef __attribute__((ext_vector_type(8))) short short8v;
typedef __attribute__((ext_vector_type(4))) float f32x4;

__device__ __forceinline__ int tri_idx(int a, int c) {      // row-major triangle (P, table frag)
    return a*Lx - (a*(a-1))/2 + (c - a);
}
__device__ __forceinline__ int qt_idx(int a, int c) {       // col-major triangle (Qt)
    return ((c*(c+1)) >> 1) + a;
}
__device__ __forceinline__ unsigned short f2bf(float x) {
    unsigned u = __float_as_uint(x);
    unsigned r = (u + 0x7FFFu + ((u >> 16) & 1u)) >> 16;
    return (unsigned short)r;
}
__device__ __forceinline__ float bf2f(unsigned short h) {
    return __uint_as_float((unsigned)h << 16);
}
__device__ __forceinline__ size_t frag_i(int r, int c) {
    return (size_t)(r >> 4)*8192 + (c >> 3)*128 + (r & 15)*8 + (c & 7);
}
__device__ __forceinline__ unsigned pk_add_f16(unsigned a, unsigned b) {
    unsigned r;
    asm("v_pk_add_f16 %0, %1, %2" : "=v"(r) : "v"(a), "v"(b));
    return r;
}
__device__ __forceinline__ unsigned pk_max_f16(unsigned a, unsigned b) {
    unsigned r;
    asm("v_pk_max_f16 %0, %1, %2" : "=v"(r) : "v"(a), "v"(b));
    return r;
}
__device__ __forceinline__ float2 h2_to_f2(unsigned u) {
    __half2 h;
    *reinterpret_cast<unsigned*>(&h) = u;
    return __half22float2(h);
}

__device__ __forceinline__ void node_epilogue(
    unsigned a0, unsigned a1, unsigned a2, unsigned a3,
    const float* __restrict__ bc, int f0, int j, int b,
    unsigned short* __restrict__ nodeH, unsigned short* __restrict__ nodeL)
{
    float4 bcA = *(const float4*)(bc + f0);
    float4 bcB = *(const float4*)(bc + f0 + 4);
    float bcv[8] = {bcA.x,bcA.y,bcA.z,bcA.w,bcB.x,bcB.y,bcB.z,bcB.w};
    unsigned am[4] = {a0,a1,a2,a3};
    unsigned uh[4], ul[4];
    #pragma unroll
    for (int e = 0; e < 4; ++e) {
        float2 x = h2_to_f2(am[e]);
        float v0 = x.x + bcv[2*e], v1 = x.y + bcv[2*e+1];
        unsigned short h0 = f2bf(v0), h1 = f2bf(v1);
        unsigned short o0 = f2bf(v0 - bf2f(h0)), o1 = f2bf(v1 - bf2f(h1));
        uh[e] = (unsigned)h0 | ((unsigned)h1 << 16);
        ul[e] = (unsigned)o0 | ((unsigned)o1 << 16);
    }
    size_t fi = (size_t)j*16384 + frag_i(b, f0);
    *(uint4*)(nodeH + fi) = make_uint4(uh[0],uh[1],uh[2],uh[3]);
    *(uint4*)(nodeL + fi) = make_uint4(ul[0],ul[1],ul[2],ul[3]);
}

// node max over cnt consecutive cells: both streams advance CELLSZ per k
__device__ __forceinline__ void node_accum2(
    const __half* __restrict__ Pb, const __half* __restrict__ Qb, int cnt,
    unsigned &A0, unsigned &A1, unsigned &A2, unsigned &A3)
{
    while (cnt >= 8) {
        uint4 vp[8], vq[8];
        #pragma unroll
        for (int u = 0; u < 8; ++u) {
            vp[u] = *(const uint4*)(Pb + (size_t)u*CELLSZ);
            vq[u] = *(const uint4*)(Qb + (size_t)u*CELLSZ);
        }
        #pragma unroll
        for (int u = 0; u < 8; ++u) {
            vp[u].x = pk_add_f16(vp[u].x, vq[u].x);
            vp[u].y = pk_add_f16(vp[u].y, vq[u].y);
            vp[u].z = pk_add_f16(vp[u].z, vq[u].z);
            vp[u].w = pk_add_f16(vp[u].w, vq[u].w);
        }
        #pragma unroll
        for (int st = 4; st >= 1; st >>= 1)
            #pragma unroll
            for (int u = 0; u < st; ++u) {
                vp[u].x = pk_max_f16(vp[u].x, vp[u+st].x);
                vp[u].y = pk_max_f16(vp[u].y, vp[u+st].y);
                vp[u].z = pk_max_f16(vp[u].z, vp[u+st].z);
                vp[u].w = pk_max_f16(vp[u].w, vp[u+st].w);
            }
        A0 = pk_max_f16(A0, vp[0].x);
        A1 = pk_max_f16(A1, vp[0].y);
        A2 = pk_max_f16(A2, vp[0].z);
        A3 = pk_max_f16(A3, vp[0].w);
        Pb += (size_t)8*CELLSZ; Qb += (size_t)8*CELLSZ; cnt -= 8;
    }
    for (; cnt > 0; --cnt) {
        uint4 vp = *(const uint4*)(Pb);
        uint4 vq = *(const uint4*)(Qb);
        A0 = pk_max_f16(A0, pk_add_f16(vp.x, vq.x));
        A1 = pk_max_f16(A1, pk_add_f16(vp.y, vq.y));
        A2 = pk_max_f16(A2, pk_add_f16(vp.z, vq.z));
        A3 = pk_max_f16(A3, pk_add_f16(vp.w, vq.w));
        Pb += CELLSZ; Qb += CELLSZ;
    }
}

// one 32-col GEMM tile for one cell: A = node frag (cell), B = BT cols [c0, c0+32)
__device__ __forceinline__ void gemm_tile32(
    int cell, int c0, int s, int l15, int lg,
    const unsigned short* __restrict__ nodeH, const unsigned short* __restrict__ nodeL,
    const unsigned short* __restrict__ BTfH, const unsigned short* __restrict__ BTfL,
    const float* __restrict__ biasBig,
    float* __restrict__ table, __half* __restrict__ P, __half* __restrict__ Qt)
{
    f32x4 acc[2][2];
    #pragma unroll
    for (int i = 0; i < 2; ++i)
        #pragma unroll
        for (int j2 = 0; j2 < 2; ++j2) acc[i][j2] = (f32x4){0.f,0.f,0.f,0.f};

    size_t lane_off = (size_t)lg*128 + l15*8;
    const unsigned short* aH = nodeH + (size_t)cell*16384 + lane_off;
    const unsigned short* aL = nodeL + (size_t)cell*16384 + lane_off;
    const unsigned short* bH = BTfH + (size_t)(c0 >> 4)*8192 + lane_off;
    const unsigned short* bL = BTfL + (size_t)(c0 >> 4)*8192 + lane_off;

    #pragma unroll 4
    for (int ks = 0; ks < 16; ++ks) {
        int ko = ks * 512;
        short8v ah0 = *(const short8v*)(aH + ko);
        short8v ah1 = *(const short8v*)(aH + ko + 8192);
        short8v al0 = *(const short8v*)(aL + ko);
        short8v al1 = *(const short8v*)(aL + ko + 8192);
        short8v bh[2], bl[2];
        #pragma unroll
        for (int cf = 0; cf < 2; ++cf) {
            bh[cf] = *(const short8v*)(bH + ko + cf*8192);
            bl[cf] = *(const short8v*)(bL + ko + cf*8192);
        }
        #pragma unroll
        for (int cf = 0; cf < 2; ++cf) {
            acc[0][cf] = __builtin_amdgcn_mfma_f32_16x16x32_bf16(ah0, bh[cf], acc[0][cf], 0, 0, 0);
            acc[1][cf] = __builtin_amdgcn_mfma_f32_16x16x32_bf16(ah1, bh[cf], acc[1][cf], 0, 0, 0);
            acc[0][cf] = __builtin_amdgcn_mfma_f32_16x16x32_bf16(al0, bh[cf], acc[0][cf], 0, 0, 0);
            acc[1][cf] = __builtin_amdgcn_mfma_f32_16x16x32_bf16(al1, bh[cf], acc[1][cf], 0, 0, 0);
            acc[0][cf] = __builtin_amdgcn_mfma_f32_16x16x32_bf16(ah0, bl[cf], acc[0][cf], 0, 0, 0);
            acc[1][cf] = __builtin_amdgcn_mfma_f32_16x16x32_bf16(ah1, bl[cf], acc[1][cf], 0, 0, 0);
        }
    }

    int tcP = tri_idx(cell, cell) + s;                  // P cell (cell, cell+s)
    int tcQ = qt_idx(cell, cell + s);                   // Qt cell (cell, cell+s)
    size_t tbl = (size_t)(cell*64 + cell + s)*CELLSZ;
    #pragma unroll
    for (int cf = 0; cf < 2; ++cf) {
        int c = c0 + cf*16 + l15;
        float bv = biasBig[c];
        #pragma unroll
        for (int rb = 0; rb < 2; ++rb)
            #pragma unroll
            for (int j2 = 0; j2 < 4; ++j2) {
                int r = rb*16 + lg*4 + j2;
                float v = acc[rb][cf][j2] + bv;
                if (c < 512)       __builtin_nontemporal_store(v, table + tbl + (size_t)r*512 + c);
                else if (c < 1024) P[(size_t)tcP*CELLSZ + (size_t)r*512 + (c-512)]  = __float2half(v);
                else               Qt[(size_t)tcQ*CELLSZ + (size_t)r*512 + (c-1024)] = __float2half(v);
            }
    }
}

// ---------------- setup kernels ----------------

__global__ void k_zero_lower(float* __restrict__ table) {
    int cell = blockIdx.x >> 4;
    int i = cell >> 6, j = cell & 63;
    if (j >= i) return;
    int sub = blockIdx.x & 15;
    f32x4* p = (f32x4*)(table + (size_t)cell*CELLSZ) + sub*256 + threadIdx.x;
    __builtin_nontemporal_store((f32x4){0.f,0.f,0.f,0.f}, p);
}

__global__ void k_lengths(const float* __restrict__ xs_mask, float* __restrict__ lengths) {
    int b = threadIdx.x;
    if (b < Bb) {
        float s = 0.f;
        for (int i = 0; i < Lx; ++i) s += xs_mask[i*Bb + b];
        lengths[b] = s;
    }
}

__global__ void k_mask(const float* __restrict__ lengths, float* __restrict__ mask_out) {
    int idx = blockIdx.x*256 + threadIdx.x;
    int b = idx & 31;
    int j = (idx >> 5) & 63;
    int i = idx >> 11;
    float v = (j >= i && (float)j < lengths[b]) ? 1.f : 0.f;
    __builtin_nontemporal_store(v, mask_out + idx);
}

__global__ void k_bias(const float* __restrict__ b2, const float* __restrict__ Wc,
                       float* __restrict__ biasBig) {
    int c = blockIdx.x*256 + threadIdx.x;
    if (c >= 1536) return;
    if (c < 512) { biasBig[c] = b2[c]; return; }
    int p = (c - 512) & 511;
    int dofs = (c < 1024) ? 0 : 512;
    float s = 0.f;
    for (int d = 0; d < 512; ++d) s += b2[d] * Wc[p*1024 + dofs + d];
    biasBig[c] = s;
}

__global__ void k_prep_xh(const float* __restrict__ xs_h,
                          unsigned short* __restrict__ xhH, unsigned short* __restrict__ xhL) {
    int gid = blockIdx.x*256 + threadIdx.x;
    int cell = gid >> 14, e = gid & 16383;
    int b = e >> 9, d = e & 511;
    float v = xs_h[gid];
    unsigned short h = f2bf(v);
    size_t fi = (size_t)cell*16384 + frag_i(b, d);
    xhH[fi] = h; xhL[fi] = f2bf(v - bf2f(h));
}

__global__ void k_prep_w1(const float* __restrict__ W1,
                          unsigned short* __restrict__ WH, unsigned short* __restrict__ WL) {
    int gid = blockIdx.x*256 + threadIdx.x;
    int c = gid >> 9, k = gid & 511;
    float v = W1[c*512 + k];
    unsigned short h = f2bf(v);
    size_t fi = frag_i(c, k);
    WH[fi] = h; WL[fi] = f2bf(v - bf2f(h));
}

__global__ void k_prep_b0(const float* __restrict__ Wc,
                          unsigned short* __restrict__ BH, unsigned short* __restrict__ BL) {
    int gid = blockIdx.x*256 + threadIdx.x;
    int c = gid >> 9, k = gid & 511;
    float v = (c < 512) ? Wc[c*1024 + k] : Wc[(c-512)*1024 + 512 + k];
    unsigned short h = f2bf(v);
    size_t fi = frag_i(c, k);
    BH[fi] = h; BL[fi] = f2bf(v - bf2f(h));
}

__global__ void k_gemm_M(const float* __restrict__ W2, const float* __restrict__ Wc,
                         float* __restrict__ BigB) {
    __shared__ float W2s[32][33];
    __shared__ float Wcs[32][33];
    int ftile = blockIdx.x & 15;
    int ptile = blockIdx.x >> 4;
    int f0 = ftile*32, p0 = ptile*32;
    int dofs  = (p0 >= 512) ? 512 : 0;
    int prow0 = (p0 >= 512) ? (p0 - 512) : p0;
    int t = threadIdx.x;
    int ff = t & 31, pg = t >> 5;
    float acc[4] = {0,0,0,0};
    for (int d0 = 0; d0 < 512; d0 += 32) {
        __syncthreads();
        #pragma unroll
        for (int i = 0; i < 4; ++i) {
            int e = t + 256*i;
            int r = e >> 5, cc = e & 31;
            W2s[r][cc] = W2[(d0 + r)*512 + f0 + cc];
            Wcs[r][cc] = Wc[(prow0 + r)*1024 + dofs + d0 + cc];
        }
        __syncthreads();
        #pragma unroll
        for (int dd = 0; dd < 32; ++dd) {
            float w = W2s[dd][ff];
            #pragma unroll
            for (int ii = 0; ii < 4; ++ii)
                acc[ii] += w * Wcs[pg*4 + ii][dd];
        }
    }
    #pragma unroll
    for (int ii = 0; ii < 4; ++ii)
        BigB[(f0 + ff)*1536 + 512 + p0 + pg*4 + ii] = acc[ii];
}

__global__ void k_makeBT(const float* __restrict__ W2, const float* __restrict__ BigB,
                         unsigned short* __restrict__ BTfH, unsigned short* __restrict__ BTfL) {
    int gid = blockIdx.x*256 + threadIdx.x;
    int c = gid >> 9, k = gid & 511;
    float v = (c < 512) ? W2[c*512 + k] : BigB[k*1536 + c];
    unsigned short h = f2bf(v);
    size_t fi = frag_i(c, k);
    BTfH[fi] = h; BTfL[fi] = f2bf(v - bf2f(h));
}

// ---------------- level-0 MFMA GEMMs ----------------
template<int MODE, int NCOLS>
__global__ __launch_bounds__(256) void k_mfma(
    const unsigned short* __restrict__ AH, const unsigned short* __restrict__ AL,
    const unsigned short* __restrict__ BH, const unsigned short* __restrict__ BL,
    const float* __restrict__ bias,
    float* __restrict__ table, __half* __restrict__ P, __half* __restrict__ Qt,
    unsigned short* __restrict__ outH, unsigned short* __restrict__ outL)
{
    constexpr int CTILES = NCOLS / 256;
    int cell = blockIdx.x / CTILES;
    int ct   = blockIdx.x % CTILES;
    int t = threadIdx.x;
    int w = t >> 6, l = t & 63;
    int l15 = l & 15, lg = l >> 4;
    int c0 = ct*256 + w*64;

    f32x4 acc[2][4];
    #pragma unroll
    for (int i = 0; i < 2; ++i)
        #pragma unroll
        for (int j = 0; j < 4; ++j) acc[i][j] = (f32x4){0.f,0.f,0.f,0.f};

    size_t lane_off = (size_t)lg*128 + l15*8;
    const unsigned short* aH = AH + (size_t)cell*16384 + lane_off;
    const unsigned short* aL = AL + (size_t)cell*16384 + lane_off;
    const unsigned short* bH = BH + (size_t)(c0 >> 4)*8192 + lane_off;
    const unsigned short* bL = BL + (size_t)(c0 >> 4)*8192 + lane_off;

    #pragma unroll 2
    for (int ks = 0; ks < 16; ++ks) {
        int ko = ks * 512;
        short8v ah0 = *(const short8v*)(aH + ko);
        short8v ah1 = *(const short8v*)(aH + ko + 8192);
        short8v al0 = *(const short8v*)(aL + ko);
        short8v al1 = *(const short8v*)(aL + ko + 8192);
        short8v bh[4], bl[4];
        #pragma unroll
        for (int cf = 0; cf < 4; ++cf) {
            bh[cf] = *(const short8v*)(bH + ko + cf*8192);
            bl[cf] = *(const short8v*)(bL + ko + cf*8192);
        }
        #pragma unroll
        for (int cf = 0; cf < 4; ++cf) {
            acc[0][cf] = __builtin_amdgcn_mfma_f32_16x16x32_bf16(ah0, bh[cf], acc[0][cf], 0, 0, 0);
            acc[1][cf] = __builtin_amdgcn_mfma_f32_16x16x32_bf16(ah1, bh[cf], acc[1][cf], 0, 0, 0);
            acc[0][cf] = __builtin_amdgcn_mfma_f32_16x16x32_bf16(al0, bh[cf], acc[0][cf], 0, 0, 0);
            acc[1][cf] = __builtin_amdgcn_mfma_f32_16x16x32_bf16(al1, bh[cf], acc[1][cf], 0, 0, 0);
            acc[0][cf] = __builtin_amdgcn_mfma_f32_16x16x32_bf16(ah0, bl[cf], acc[0][cf], 0, 0, 0);
            acc[1][cf] = __builtin_amdgcn_mfma_f32_16x16x32_bf16(ah1, bl[cf], acc[1][cf], 0, 0, 0);
        }
    }

    #pragma unroll
    for (int cf = 0; cf < 4; ++cf) {
        int c = c0 + cf*16 + l15;
        if (MODE == 0) {
            float bv = bias[c];
            size_t tbl = (size_t)(cell*65)*CELLSZ;
            #pragma unroll
            for (int rb = 0; rb < 2; ++rb)
                #pragma unroll
                for (int j = 0; j < 4; ++j) {
                    int r = rb*16 + lg*4 + j;
                    float v = acc[rb][cf][j] + bv;
                    __builtin_nontemporal_store(v, table + tbl + (size_t)r*512 + c);
                    size_t fi = (size_t)cell*16384 + frag_i(r, c);
                    unsigned short h = f2bf(v);
                    outH[fi] = h; outL[fi] = f2bf(v - bf2f(h));
                }
        } else {
            int tcP = tri_idx(cell, cell);
            int tcQ = qt_idx(cell, cell);
            __half* dst = (c < 512) ? (P + (size_t)tcP*CELLSZ) : (Qt + (size_t)tcQ*CELLSZ);
            int cc = c & 511;
            #pragma unroll
            for (int rb = 0; rb < 2; ++rb)
                #pragma unroll
                for (int j = 0; j < 4; ++j) {
                    int r = rb*16 + lg*4 + j;
                    dst[(size_t)r*512 + cc] = __float2half(acc[rb][cf][j]);
                }
        }
    }
}

// ---------------- per-level node kernel ----------------
// grid = n*8*KC blocks x 256 thr (4 waves; wave covers one b, lane owns 8 f).
// KC==1: frag-major node out, separate wide GEMM follows.
// KC>1 : fp16 partial out; LAST block (per cell) reduces + runs the cell's GEMM.
__global__ __launch_bounds__(256, 4) void k_node_ml(
    const __half* __restrict__ P, const __half* __restrict__ Qt,
    const float* __restrict__ bc,
    unsigned short* __restrict__ nodeH, unsigned short* __restrict__ nodeL,
    __half* __restrict__ nodePart,
    const unsigned short* __restrict__ BTfH, const unsigned short* __restrict__ BTfL,
    const float* __restrict__ biasBig,
    float* __restrict__ table, __half* __restrict__ Pw, __half* __restrict__ Qtw,
    int* __restrict__ done, int s, int KC)
{
    int per_j = KC << 3;
    int j   = blockIdx.x / per_j;
    int rem = blockIdx.x - j*per_j;
    int kc  = rem >> 3, bq = rem & 7;
    int t = threadIdx.x;
    int b  = bq*4 + (t >> 6);
    int f0 = (t & 63) * 8;
    int k0 = (s*kc)/KC, k1 = (s*(kc+1))/KC;

    unsigned A0 = 0xFC00FC00u, A1 = A0, A2 = A0, A3 = A0;
    int C = j + s;
    const __half* Pb = P  + (size_t)(tri_idx(j, j) + k0)*CELLSZ + b*512 + f0;
    const __half* Qb = Qt + (size_t)(qt_idx(j + 1, C) + k0)*CELLSZ + b*512 + f0;
    node_accum2(Pb, Qb, k1 - k0, A0, A1, A2, A3);

    if (KC == 1) {
        node_epilogue(A0, A1, A2, A3, bc, f0, j, b, nodeH, nodeL);
        return;
    }

    *(uint4*)(nodePart + (size_t)(kc*32 + j)*CELLSZ + b*512 + f0) =
        make_uint4(A0, A1, A2, A3);

    // ---- last-block protocol (gbar-style release/acquire) ----
    __shared__ int lastFlag;
    __syncthreads();
    if (t == 0) {
        int old = __hip_atomic_fetch_add(&done[(s << 6) + j], 1,
                                         __ATOMIC_RELEASE, __HIP_MEMORY_SCOPE_AGENT);
        lastFlag = (old == (KC << 3) - 1);
        if (lastFlag) __builtin_amdgcn_fence(__ATOMIC_ACQUIRE, "agent");
    }
    __syncthreads();
    if (!lastFlag) return;

    // ---- reduce whole cell j (8 iterations of 4 b's) ----
    int bw = t >> 6;
    #pragma unroll
    for (int bb = 0; bb < 8; ++bb) {
        int b2 = bw + 4*bb;
        const __half* base = nodePart + (size_t)j*CELLSZ + b2*512 + f0;
        uint4 v = *(const uint4*)(base);
        unsigned R0 = v.x, R1 = v.y, R2 = v.z, R3 = v.w;
        for (int c2 = 1; c2 < KC; ++c2) {
            uint4 w2 = *(const uint4*)(base + (size_t)c2*32*CELLSZ);
            R0 = pk_max_f16(R0, w2.x);
            R1 = pk_max_f16(R1, w2.y);
            R2 = pk_max_f16(R2, w2.z);
            R3 = pk_max_f16(R3, w2.w);
        }
        node_epilogue(R0, R1, R2, R3, bc, f0, j, b2, nodeH, nodeL);
    }
    __syncthreads();   // node writes visible to whole block (same L2)

    // ---- fused GEMM: 48 tiles over 4 waves (12 each) ----
    int l = t & 63;
    int l15 = l & 15, lg = l >> 4;
    int w = t >> 6;
    for (int tt = 0; tt < 12; ++tt) {
        int c0 = (tt*4 + w) * 32;
        gemm_tile32(j, c0, s, l15, lg, nodeH, nodeL, BTfH, BTfL, biasBig,
                    table, Pw, Qtw);
    }
}

// ---------------- per-level GEMM (KC==1 levels): 1-wave blocks, 32-col tiles ----------------
__global__ __launch_bounds__(64, 4) void k_gemm_ml(
    const unsigned short* __restrict__ nodeH, const unsigned short* __restrict__ nodeL,
    const unsigned short* __restrict__ BTfH, const unsigned short* __restrict__ BTfL,
    const float* __restrict__ biasBig,
    float* __restrict__ table, __half* __restrict__ P, __half* __restrict__ Qt, int s)
{
    int cell = blockIdx.x / 48;
    int tile = blockIdx.x - cell*48;
    int l = threadIdx.x;
    gemm_tile32(cell, tile*32, s, l & 15, l >> 4, nodeH, nodeL, BTfH, BTfL, biasBig,
                table, P, Qt);
}

// ---------------- launch ----------------

extern "C" void kernel_launch(void* const* d_in, const int* in_sizes, int n_in,
                              void* d_out, int out_size, void* d_ws, size_t ws_size,
                              hipStream_t stream) {
    const float* xs_h    = (const float*)d_in[0];
    const float* xs_mask = (const float*)d_in[1];
    const float* W1      = (const float*)d_in[2];
    const float* b1      = (const float*)d_in[3];
    const float* Wc      = (const float*)d_in[4];
    const float* bc      = (const float*)d_in[5];
    const float* W2      = (const float*)d_in[6];
    const float* b2      = (const float*)d_in[7];

    float* table   = (float*)d_out;                     // 64*64*32*512 f32
    float* maskout = table + 67108864;                  // 64*64*32

    __half* P  = (__half*)d_ws;                         // 2080*16384 halves (row-tri)
    __half* Qt = P + 34078720;                          // 2080*16384 halves (col-tri)
    unsigned short* nodeH = (unsigned short*)(Qt + 34078720);  // 63*16384
    unsigned short* nodeL = nodeH + 1032192;
    unsigned short* xhH   = nodeL + 1032192;            // 64*16384
    unsigned short* xhL   = xhH + 1048576;
    unsigned short* diagH = xhL + 1048576;              // 64*16384
    unsigned short* diagL = diagH + 1048576;
    unsigned short* W1fH  = diagL + 1048576;            // 512*512
    unsigned short* W1fL  = W1fH + 262144;
    unsigned short* B0fH  = W1fL + 262144;              // 1024*512
    unsigned short* B0fL  = B0fH + 524288;
    unsigned short* BTfH  = B0fL + 524288;              // 1536*512
    unsigned short* BTfL  = BTfH + 786432;
    float* BigB    = (float*)(BTfL + 786432);           // 512*1536 f32
    float* biasBig = BigB + 786432;                     // 1536
    float* lengths = biasBig + 1536;                    // 32
    int*   done    = (int*)(lengths + 64);              // 64*64 counters
    __half* nodePart = (__half*)(done + 4096);          // 256*16384 halves (KC partials)

    (void)hipMemsetAsync(done, 0, 4096*4, stream);
    k_zero_lower<<<65536, 256, 0, stream>>>(table);
    k_lengths<<<1, 64, 0, stream>>>(xs_mask, lengths);
    k_mask<<<512, 256, 0, stream>>>(lengths, maskout);
    k_prep_xh<<<4096, 256, 0, stream>>>(xs_h, xhH, xhL);
    k_prep_w1<<<1024, 256, 0, stream>>>(W1, W1fH, W1fL);
    k_prep_b0<<<2048, 256, 0, stream>>>(Wc, B0fH, B0fL);
    k_gemm_M<<<512, 256, 0, stream>>>(W2, Wc, BigB);
    k_bias<<<6, 256, 0, stream>>>(b2, Wc, biasBig);
    k_makeBT<<<3072, 256, 0, stream>>>(W2, BigB, BTfH, BTfL);

    // level 0: diag (emits frag-major diag too), then P/Qt projections
    k_mfma<0, 512><<<64*2, 256, 0, stream>>>(xhH, xhL, W1fH, W1fL, b1,
                                             table, nullptr, nullptr, diagH, diagL);
    k_mfma<1, 1024><<<64*4, 256, 0, stream>>>(diagH, diagL, B0fH, B0fL, nullptr,
                                              table, P, Qt, nullptr, nullptr);

    for (int s = 1; s < 64; ++s) {
        int n = 64 - s;
        int KC = (n >= 32) ? 1 : (n >= 16) ? 2 : (n >= 4) ? 4 : 8;
        k_node_ml<<<n*8*KC, 256, 0, stream>>>(P, Qt, bc, nodeH, nodeL, nodePart,
                                              BTfH, BTfL, biasBig, table, P, Qt,
                                              done, s, KC);
        if (KC == 1)
            k_gemm_ml<<<n*48, 64, 0, stream>>>(nodeH, nodeL, BTfH, BTfL, biasBig,
                                               table, P, Qt, s);
    }
}

// Round 12
// 1627.487 us; speedup vs baseline: 3.0819x; 3.0819x over previous
//
#include <hip/hip_runtime.h>
#include <hip/hip_fp16.h>

// CYK net: L=64, B=32, DIN=D=FFS=512
//   P[cell] = table[cell] @ WcL.T (row-tri layout); Qt[cell] = table[cell] @ WcR.T (col-tri layout)
//   node(j,s) = bc + max_k ( P[j,j+k] + Qt[j+k+1,j+s] )   -- BOTH streams contiguous in k
//   [vals|P|Qt] = node @ BigB + biasBig   (bf16x3 MFMA)
// R11 -> R12: REVERT the last-block fusion (it serialized 48 GEMM tiles onto one
// block per cell: 155us tail dispatches @ 2.7% occupancy). Back to R10's separate
// k_node_red + wide k_gemm_ml. KEEP the Qt col-triangle layout (proven correct in
// R11; makes both node streams advance +CELLSZ per k).

#define Lx 64
#define Bb 32
#define CELLSZ (Bb*512)         // 16384 elems per cell tile

typedef __attribute__((ext_vector_type(8))) short short8v;
typedef __attribute__((ext_vector_type(4))) float f32x4;

__device__ __forceinline__ int tri_idx(int a, int c) {      // row-major triangle (P, table frag)
    return a*Lx - (a*(a-1))/2 + (c - a);
}
__device__ __forceinline__ int qt_idx(int a, int c) {       // col-major triangle (Qt)
    return ((c*(c+1)) >> 1) + a;
}
__device__ __forceinline__ unsigned short f2bf(float x) {
    unsigned u = __float_as_uint(x);
    unsigned r = (u + 0x7FFFu + ((u >> 16) & 1u)) >> 16;
    return (unsigned short)r;
}
__device__ __forceinline__ float bf2f(unsigned short h) {
    return __uint_as_float((unsigned)h << 16);
}
__device__ __forceinline__ size_t frag_i(int r, int c) {
    return (size_t)(r >> 4)*8192 + (c >> 3)*128 + (r & 15)*8 + (c & 7);
}
__device__ __forceinline__ unsigned pk_add_f16(unsigned a, unsigned b) {
    unsigned r;
    asm("v_pk_add_f16 %0, %1, %2" : "=v"(r) : "v"(a), "v"(b));
    return r;
}
__device__ __forceinline__ unsigned pk_max_f16(unsigned a, unsigned b) {
    unsigned r;
    asm("v_pk_max_f16 %0, %1, %2" : "=v"(r) : "v"(a), "v"(b));
    return r;
}
__device__ __forceinline__ float2 h2_to_f2(unsigned u) {
    __half2 h;
    *reinterpret_cast<unsigned*>(&h) = u;
    return __half22float2(h);
}

__device__ __forceinline__ void node_epilogue(
    unsigned a0, unsigned a1, unsigned a2, unsigned a3,
    const float* __restrict__ bc, int f0, int j, int b,
    unsigned short* __restrict__ nodeH, unsigned short* __restrict__ nodeL)
{
    float4 bcA = *(const float4*)(bc + f0);
    float4 bcB = *(const float4*)(bc + f0 + 4);
    float bcv[8] = {bcA.x,bcA.y,bcA.z,bcA.w,bcB.x,bcB.y,bcB.z,bcB.w};
    unsigned am[4] = {a0,a1,a2,a3};
    unsigned uh[4], ul[4];
    #pragma unroll
    for (int e = 0; e < 4; ++e) {
        float2 x = h2_to_f2(am[e]);
        float v0 = x.x + bcv[2*e], v1 = x.y + bcv[2*e+1];
        unsigned short h0 = f2bf(v0), h1 = f2bf(v1);
        unsigned short o0 = f2bf(v0 - bf2f(h0)), o1 = f2bf(v1 - bf2f(h1));
        uh[e] = (unsigned)h0 | ((unsigned)h1 << 16);
        ul[e] = (unsigned)o0 | ((unsigned)o1 << 16);
    }
    size_t fi = (size_t)j*16384 + frag_i(b, f0);
    *(uint4*)(nodeH + fi) = make_uint4(uh[0],uh[1],uh[2],uh[3]);
    *(uint4*)(nodeL + fi) = make_uint4(ul[0],ul[1],ul[2],ul[3]);
}

// node max over cnt consecutive cells: both streams advance CELLSZ per k
__device__ __forceinline__ void node_accum2(
    const __half* __restrict__ Pb, const __half* __restrict__ Qb, int cnt,
    unsigned &A0, unsigned &A1, unsigned &A2, unsigned &A3)
{
    while (cnt >= 8) {
        uint4 vp[8], vq[8];
        #pragma unroll
        for (int u = 0; u < 8; ++u) {
            vp[u] = *(const uint4*)(Pb + (size_t)u*CELLSZ);
            vq[u] = *(const uint4*)(Qb + (size_t)u*CELLSZ);
        }
        #pragma unroll
        for (int u = 0; u < 8; ++u) {
            vp[u].x = pk_add_f16(vp[u].x, vq[u].x);
            vp[u].y = pk_add_f16(vp[u].y, vq[u].y);
            vp[u].z = pk_add_f16(vp[u].z, vq[u].z);
            vp[u].w = pk_add_f16(vp[u].w, vq[u].w);
        }
        #pragma unroll
        for (int st = 4; st >= 1; st >>= 1)
            #pragma unroll
            for (int u = 0; u < st; ++u) {
                vp[u].x = pk_max_f16(vp[u].x, vp[u+st].x);
                vp[u].y = pk_max_f16(vp[u].y, vp[u+st].y);
                vp[u].z = pk_max_f16(vp[u].z, vp[u+st].z);
                vp[u].w = pk_max_f16(vp[u].w, vp[u+st].w);
            }
        A0 = pk_max_f16(A0, vp[0].x);
        A1 = pk_max_f16(A1, vp[0].y);
        A2 = pk_max_f16(A2, vp[0].z);
        A3 = pk_max_f16(A3, vp[0].w);
        Pb += (size_t)8*CELLSZ; Qb += (size_t)8*CELLSZ; cnt -= 8;
    }
    for (; cnt > 0; --cnt) {
        uint4 vp = *(const uint4*)(Pb);
        uint4 vq = *(const uint4*)(Qb);
        A0 = pk_max_f16(A0, pk_add_f16(vp.x, vq.x));
        A1 = pk_max_f16(A1, pk_add_f16(vp.y, vq.y));
        A2 = pk_max_f16(A2, pk_add_f16(vp.z, vq.z));
        A3 = pk_max_f16(A3, pk_add_f16(vp.w, vq.w));
        Pb += CELLSZ; Qb += CELLSZ;
    }
}

// ---------------- setup kernels ----------------

__global__ void k_zero_lower(float* __restrict__ table) {
    int cell = blockIdx.x >> 4;
    int i = cell >> 6, j = cell & 63;
    if (j >= i) return;
    int sub = blockIdx.x & 15;
    f32x4* p = (f32x4*)(table + (size_t)cell*CELLSZ) + sub*256 + threadIdx.x;
    __builtin_nontemporal_store((f32x4){0.f,0.f,0.f,0.f}, p);
}

__global__ void k_lengths(const float* __restrict__ xs_mask, float* __restrict__ lengths) {
    int b = threadIdx.x;
    if (b < Bb) {
        float s = 0.f;
        for (int i = 0; i < Lx; ++i) s += xs_mask[i*Bb + b];
        lengths[b] = s;
    }
}

__global__ void k_mask(const float* __restrict__ lengths, float* __restrict__ mask_out) {
    int idx = blockIdx.x*256 + threadIdx.x;
    int b = idx & 31;
    int j = (idx >> 5) & 63;
    int i = idx >> 11;
    float v = (j >= i && (float)j < lengths[b]) ? 1.f : 0.f;
    __builtin_nontemporal_store(v, mask_out + idx);
}

__global__ void k_bias(const float* __restrict__ b2, const float* __restrict__ Wc,
                       float* __restrict__ biasBig) {
    int c = blockIdx.x*256 + threadIdx.x;
    if (c >= 1536) return;
    if (c < 512) { biasBig[c] = b2[c]; return; }
    int p = (c - 512) & 511;
    int dofs = (c < 1024) ? 0 : 512;
    float s = 0.f;
    for (int d = 0; d < 512; ++d) s += b2[d] * Wc[p*1024 + dofs + d];
    biasBig[c] = s;
}

__global__ void k_prep_xh(const float* __restrict__ xs_h,
                          unsigned short* __restrict__ xhH, unsigned short* __restrict__ xhL) {
    int gid = blockIdx.x*256 + threadIdx.x;
    int cell = gid >> 14, e = gid & 16383;
    int b = e >> 9, d = e & 511;
    float v = xs_h[gid];
    unsigned short h = f2bf(v);
    size_t fi = (size_t)cell*16384 + frag_i(b, d);
    xhH[fi] = h; xhL[fi] = f2bf(v - bf2f(h));
}

__global__ void k_prep_w1(const float* __restrict__ W1,
                          unsigned short* __restrict__ WH, unsigned short* __restrict__ WL) {
    int gid = blockIdx.x*256 + threadIdx.x;
    int c = gid >> 9, k = gid & 511;
    float v = W1[c*512 + k];
    unsigned short h = f2bf(v);
    size_t fi = frag_i(c, k);
    WH[fi] = h; WL[fi] = f2bf(v - bf2f(h));
}

__global__ void k_prep_b0(const float* __restrict__ Wc,
                          unsigned short* __restrict__ BH, unsigned short* __restrict__ BL) {
    int gid = blockIdx.x*256 + threadIdx.x;
    int c = gid >> 9, k = gid & 511;
    float v = (c < 512) ? Wc[c*1024 + k] : Wc[(c-512)*1024 + 512 + k];
    unsigned short h = f2bf(v);
    size_t fi = frag_i(c, k);
    BH[fi] = h; BL[fi] = f2bf(v - bf2f(h));
}

__global__ void k_gemm_M(const float* __restrict__ W2, const float* __restrict__ Wc,
                         float* __restrict__ BigB) {
    __shared__ float W2s[32][33];
    __shared__ float Wcs[32][33];
    int ftile = blockIdx.x & 15;
    int ptile = blockIdx.x >> 4;
    int f0 = ftile*32, p0 = ptile*32;
    int dofs  = (p0 >= 512) ? 512 : 0;
    int prow0 = (p0 >= 512) ? (p0 - 512) : p0;
    int t = threadIdx.x;
    int ff = t & 31, pg = t >> 5;
    float acc[4] = {0,0,0,0};
    for (int d0 = 0; d0 < 512; d0 += 32) {
        __syncthreads();
        #pragma unroll
        for (int i = 0; i < 4; ++i) {
            int e = t + 256*i;
            int r = e >> 5, cc = e & 31;
            W2s[r][cc] = W2[(d0 + r)*512 + f0 + cc];
            Wcs[r][cc] = Wc[(prow0 + r)*1024 + dofs + d0 + cc];
        }
        __syncthreads();
        #pragma unroll
        for (int dd = 0; dd < 32; ++dd) {
            float w = W2s[dd][ff];
            #pragma unroll
            for (int ii = 0; ii < 4; ++ii)
                acc[ii] += w * Wcs[pg*4 + ii][dd];
        }
    }
    #pragma unroll
    for (int ii = 0; ii < 4; ++ii)
        BigB[(f0 + ff)*1536 + 512 + p0 + pg*4 + ii] = acc[ii];
}

__global__ void k_makeBT(const float* __restrict__ W2, const float* __restrict__ BigB,
                         unsigned short* __restrict__ BTfH, unsigned short* __restrict__ BTfL) {
    int gid = blockIdx.x*256 + threadIdx.x;
    int c = gid >> 9, k = gid & 511;
    float v = (c < 512) ? W2[c*512 + k] : BigB[k*1536 + c];
    unsigned short h = f2bf(v);
    size_t fi = frag_i(c, k);
    BTfH[fi] = h; BTfL[fi] = f2bf(v - bf2f(h));
}

// ---------------- level-0 MFMA GEMMs ----------------
template<int MODE, int NCOLS>
__global__ __launch_bounds__(256) void k_mfma(
    const unsigned short* __restrict__ AH, const unsigned short* __restrict__ AL,
    const unsigned short* __restrict__ BH, const unsigned short* __restrict__ BL,
    const float* __restrict__ bias,
    float* __restrict__ table, __half* __restrict__ P, __half* __restrict__ Qt,
    unsigned short* __restrict__ outH, unsigned short* __restrict__ outL)
{
    constexpr int CTILES = NCOLS / 256;
    int cell = blockIdx.x / CTILES;
    int ct   = blockIdx.x % CTILES;
    int t = threadIdx.x;
    int w = t >> 6, l = t & 63;
    int l15 = l & 15, lg = l >> 4;
    int c0 = ct*256 + w*64;

    f32x4 acc[2][4];
    #pragma unroll
    for (int i = 0; i < 2; ++i)
        #pragma unroll
        for (int j = 0; j < 4; ++j) acc[i][j] = (f32x4){0.f,0.f,0.f,0.f};

    size_t lane_off = (size_t)lg*128 + l15*8;
    const unsigned short* aH = AH + (size_t)cell*16384 + lane_off;
    const unsigned short* aL = AL + (size_t)cell*16384 + lane_off;
    const unsigned short* bH = BH + (size_t)(c0 >> 4)*8192 + lane_off;
    const unsigned short* bL = BL + (size_t)(c0 >> 4)*8192 + lane_off;

    #pragma unroll 2
    for (int ks = 0; ks < 16; ++ks) {
        int ko = ks * 512;
        short8v ah0 = *(const short8v*)(aH + ko);
        short8v ah1 = *(const short8v*)(aH + ko + 8192);
        short8v al0 = *(const short8v*)(aL + ko);
        short8v al1 = *(const short8v*)(aL + ko + 8192);
        short8v bh[4], bl[4];
        #pragma unroll
        for (int cf = 0; cf < 4; ++cf) {
            bh[cf] = *(const short8v*)(bH + ko + cf*8192);
            bl[cf] = *(const short8v*)(bL + ko + cf*8192);
        }
        #pragma unroll
        for (int cf = 0; cf < 4; ++cf) {
            acc[0][cf] = __builtin_amdgcn_mfma_f32_16x16x32_bf16(ah0, bh[cf], acc[0][cf], 0, 0, 0);
            acc[1][cf] = __builtin_amdgcn_mfma_f32_16x16x32_bf16(ah1, bh[cf], acc[1][cf], 0, 0, 0);
            acc[0][cf] = __builtin_amdgcn_mfma_f32_16x16x32_bf16(al0, bh[cf], acc[0][cf], 0, 0, 0);
            acc[1][cf] = __builtin_amdgcn_mfma_f32_16x16x32_bf16(al1, bh[cf], acc[1][cf], 0, 0, 0);
            acc[0][cf] = __builtin_amdgcn_mfma_f32_16x16x32_bf16(ah0, bl[cf], acc[0][cf], 0, 0, 0);
            acc[1][cf] = __builtin_amdgcn_mfma_f32_16x16x32_bf16(ah1, bl[cf], acc[1][cf], 0, 0, 0);
        }
    }

    #pragma unroll
    for (int cf = 0; cf < 4; ++cf) {
        int c = c0 + cf*16 + l15;
        if (MODE == 0) {
            float bv = bias[c];
            size_t tbl = (size_t)(cell*65)*CELLSZ;
            #pragma unroll
            for (int rb = 0; rb < 2; ++rb)
                #pragma unroll
                for (int j = 0; j < 4; ++j) {
                    int r = rb*16 + lg*4 + j;
                    float v = acc[rb][cf][j] + bv;
                    __builtin_nontemporal_store(v, table + tbl + (size_t)r*512 + c);
                    size_t fi = (size_t)cell*16384 + frag_i(r, c);
                    unsigned short h = f2bf(v);
                    outH[fi] = h; outL[fi] = f2bf(v - bf2f(h));
                }
        } else {
            int tcP = tri_idx(cell, cell);
            int tcQ = qt_idx(cell, cell);
            __half* dst = (c < 512) ? (P + (size_t)tcP*CELLSZ) : (Qt + (size_t)tcQ*CELLSZ);
            int cc = c & 511;
            #pragma unroll
            for (int rb = 0; rb < 2; ++rb)
                #pragma unroll
                for (int j = 0; j < 4; ++j) {
                    int r = rb*16 + lg*4 + j;
                    dst[(size_t)r*512 + cc] = __float2half(acc[rb][cf][j]);
                }
        }
    }
}

// ---------------- per-level node kernel ----------------
// grid = n*8*KC blocks x 256 thr (4 waves; wave covers one b, lane owns 8 f).
__global__ __launch_bounds__(256, 4) void k_node_ml(
    const __half* __restrict__ P, const __half* __restrict__ Qt,
    const float* __restrict__ bc,
    unsigned short* __restrict__ nodeH, unsigned short* __restrict__ nodeL,
    __half* __restrict__ nodePart, int s, int KC)
{
    int per_j = KC << 3;
    int j   = blockIdx.x / per_j;
    int rem = blockIdx.x - j*per_j;
    int kc  = rem >> 3, bq = rem & 7;
    int t = threadIdx.x;
    int b  = bq*4 + (t >> 6);
    int f0 = (t & 63) * 8;
    int k0 = (s*kc)/KC, k1 = (s*(kc+1))/KC;

    unsigned A0 = 0xFC00FC00u, A1 = A0, A2 = A0, A3 = A0;
    const __half* Pb = P  + (size_t)(tri_idx(j, j) + k0)*CELLSZ + b*512 + f0;
    const __half* Qb = Qt + (size_t)(qt_idx(j + 1, j + s) + k0)*CELLSZ + b*512 + f0;
    node_accum2(Pb, Qb, k1 - k0, A0, A1, A2, A3);

    if (KC == 1) {
        node_epilogue(A0, A1, A2, A3, bc, f0, j, b, nodeH, nodeL);
    } else {
        *(uint4*)(nodePart + (size_t)(kc*32 + j)*CELLSZ + b*512 + f0) =
            make_uint4(A0, A1, A2, A3);
    }
}

// ---------------- node reduce (tail levels) ----------------
__global__ __launch_bounds__(256) void k_node_red(
    const __half* __restrict__ nodePart, const float* __restrict__ bc,
    unsigned short* __restrict__ nodeH, unsigned short* __restrict__ nodeL, int KC)
{
    int j  = blockIdx.x >> 3;
    int bq = blockIdx.x & 7;
    int t = threadIdx.x;
    int b  = bq*4 + (t >> 6);
    int f0 = (t & 63) * 8;
    const __half* base = nodePart + (size_t)j*CELLSZ + b*512 + f0;
    uint4 v = *(const uint4*)(base);
    unsigned A0 = v.x, A1 = v.y, A2 = v.z, A3 = v.w;
    for (int kc = 1; kc < KC; ++kc) {
        uint4 w = *(const uint4*)(base + (size_t)kc*32*CELLSZ);
        A0 = pk_max_f16(A0, w.x);
        A1 = pk_max_f16(A1, w.y);
        A2 = pk_max_f16(A2, w.z);
        A3 = pk_max_f16(A3, w.w);
    }
    node_epilogue(A0, A1, A2, A3, bc, f0, j, b, nodeH, nodeL);
}

// ---------------- per-level GEMM: 1-wave blocks, 32-col tiles ----------------
__global__ __launch_bounds__(64, 4) void k_gemm_ml(
    const unsigned short* __restrict__ nodeH, const unsigned short* __restrict__ nodeL,
    const unsigned short* __restrict__ BTfH, const unsigned short* __restrict__ BTfL,
    const float* __restrict__ biasBig,
    float* __restrict__ table, __half* __restrict__ P, __half* __restrict__ Qt, int s)
{
    int cell = blockIdx.x / 48;
    int tile = blockIdx.x - cell*48;
    int c0   = tile*32;
    int l = threadIdx.x;
    int l15 = l & 15, lg = l >> 4;

    f32x4 acc[2][2];
    #pragma unroll
    for (int i = 0; i < 2; ++i)
        #pragma unroll
        for (int j2 = 0; j2 < 2; ++j2) acc[i][j2] = (f32x4){0.f,0.f,0.f,0.f};

    size_t lane_off = (size_t)lg*128 + l15*8;
    const unsigned short* aH = nodeH + (size_t)cell*16384 + lane_off;
    const unsigned short* aL = nodeL + (size_t)cell*16384 + lane_off;
    const unsigned short* bH = BTfH + (size_t)(c0 >> 4)*8192 + lane_off;
    const unsigned short* bL = BTfL + (size_t)(c0 >> 4)*8192 + lane_off;

    #pragma unroll 4
    for (int ks = 0; ks < 16; ++ks) {
        int ko = ks * 512;
        short8v ah0 = *(const short8v*)(aH + ko);
        short8v ah1 = *(const short8v*)(aH + ko + 8192);
        short8v al0 = *(const short8v*)(aL + ko);
        short8v al1 = *(const short8v*)(aL + ko + 8192);
        short8v bh[2], bl[2];
        #pragma unroll
        for (int cf = 0; cf < 2; ++cf) {
            bh[cf] = *(const short8v*)(bH + ko + cf*8192);
            bl[cf] = *(const short8v*)(bL + ko + cf*8192);
        }
        #pragma unroll
        for (int cf = 0; cf < 2; ++cf) {
            acc[0][cf] = __builtin_amdgcn_mfma_f32_16x16x32_bf16(ah0, bh[cf], acc[0][cf], 0, 0, 0);
            acc[1][cf] = __builtin_amdgcn_mfma_f32_16x16x32_bf16(ah1, bh[cf], acc[1][cf], 0, 0, 0);
            acc[0][cf] = __builtin_amdgcn_mfma_f32_16x16x32_bf16(al0, bh[cf], acc[0][cf], 0, 0, 0);
            acc[1][cf] = __builtin_amdgcn_mfma_f32_16x16x32_bf16(al1, bh[cf], acc[1][cf], 0, 0, 0);
            acc[0][cf] = __builtin_amdgcn_mfma_f32_16x16x32_bf16(ah0, bl[cf], acc[0][cf], 0, 0, 0);
            acc[1][cf] = __builtin_amdgcn_mfma_f32_16x16x32_bf16(ah1, bl[cf], acc[1][cf], 0, 0, 0);
        }
    }

    int tcP = tri_idx(cell, cell) + s;
    int tcQ = qt_idx(cell, cell + s);
    size_t tbl = (size_t)(cell*64 + cell + s)*CELLSZ;
    #pragma unroll
    for (int cf = 0; cf < 2; ++cf) {
        int c = c0 + cf*16 + l15;
        float bv = biasBig[c];
        #pragma unroll
        for (int rb = 0; rb < 2; ++rb)
            #pragma unroll
            for (int j2 = 0; j2 < 4; ++j2) {
                int r = rb*16 + lg*4 + j2;
                float v = acc[rb][cf][j2] + bv;
                if (c < 512)       __builtin_nontemporal_store(v, table + tbl + (size_t)r*512 + c);
                else if (c < 1024) P[(size_t)tcP*CELLSZ + (size_t)r*512 + (c-512)]  = __float2half(v);
                else               Qt[(size_t)tcQ*CELLSZ + (size_t)r*512 + (c-1024)] = __float2half(v);
            }
    }
}

// ---------------- launch ----------------

extern "C" void kernel_launch(void* const* d_in, const int* in_sizes, int n_in,
                              void* d_out, int out_size, void* d_ws, size_t ws_size,
                              hipStream_t stream) {
    const float* xs_h    = (const float*)d_in[0];
    const float* xs_mask = (const float*)d_in[1];
    const float* W1      = (const float*)d_in[2];
    const float* b1      = (const float*)d_in[3];
    const float* Wc      = (const float*)d_in[4];
    const float* bc      = (const float*)d_in[5];
    const float* W2      = (const float*)d_in[6];
    const float* b2      = (const float*)d_in[7];

    float* table   = (float*)d_out;                     // 64*64*32*512 f32
    float* maskout = table + 67108864;                  // 64*64*32

    __half* P  = (__half*)d_ws;                         // 2080*16384 halves (row-tri)
    __half* Qt = P + 34078720;                          // 2080*16384 halves (col-tri)
    unsigned short* nodeH = (unsigned short*)(Qt + 34078720);  // 63*16384
    unsigned short* nodeL = nodeH + 1032192;
    unsigned short* xhH   = nodeL + 1032192;            // 64*16384
    unsigned short* xhL   = xhH + 1048576;
    unsigned short* diagH = xhL + 1048576;              // 64*16384
    unsigned short* diagL = diagH + 1048576;
    unsigned short* W1fH  = diagL + 1048576;            // 512*512
    unsigned short* W1fL  = W1fH + 262144;
    unsigned short* B0fH  = W1fL + 262144;              // 1024*512
    unsigned short* B0fL  = B0fH + 524288;
    unsigned short* BTfH  = B0fL + 524288;              // 1536*512
    unsigned short* BTfL  = BTfH + 786432;
    float* BigB    = (float*)(BTfL + 786432);           // 512*1536 f32
    float* biasBig = BigB + 786432;                     // 1536
    float* lengths = biasBig + 1536;                    // 32
    __half* nodePart = (__half*)(lengths + 64);         // 256*16384 halves (KC partials)

    k_zero_lower<<<65536, 256, 0, stream>>>(table);
    k_lengths<<<1, 64, 0, stream>>>(xs_mask, lengths);
    k_mask<<<512, 256, 0, stream>>>(lengths, maskout);
    k_prep_xh<<<4096, 256, 0, stream>>>(xs_h, xhH, xhL);
    k_prep_w1<<<1024, 256, 0, stream>>>(W1, W1fH, W1fL);
    k_prep_b0<<<2048, 256, 0, stream>>>(Wc, B0fH, B0fL);
    k_gemm_M<<<512, 256, 0, stream>>>(W2, Wc, BigB);
    k_bias<<<6, 256, 0, stream>>>(b2, Wc, biasBig);
    k_makeBT<<<3072, 256, 0, stream>>>(W2, BigB, BTfH, BTfL);

    // level 0: diag (emits frag-major diag too), then P/Qt projections
    k_mfma<0, 512><<<64*2, 256, 0, stream>>>(xhH, xhL, W1fH, W1fL, b1,
                                             table, nullptr, nullptr, diagH, diagL);
    k_mfma<1, 1024><<<64*4, 256, 0, stream>>>(diagH, diagL, B0fH, B0fL, nullptr,
                                              table, P, Qt, nullptr, nullptr);

    for (int s = 1; s < 64; ++s) {
        int n = 64 - s;
        int KC = (n >= 32) ? 1 : (n >= 16) ? 2 : (n >= 4) ? 4 : 8;
        k_node_ml<<<n*8*KC, 256, 0, stream>>>(P, Qt, bc, nodeH, nodeL, nodePart, s, KC);
        if (KC > 1)
            k_node_red<<<n*8, 256, 0, stream>>>(nodePart, bc, nodeH, nodeL, KC);
        k_gemm_ml<<<n*48, 64, 0, stream>>>(nodeH, nodeL, BTfH, BTfL, biasBig,
                                           table, P, Qt, s);
    }
}